// Round 11
// baseline (91.934 us; speedup 1.0000x reference)
//
#include <hip/hip_runtime.h>
#include <hip/hip_bf16.h>
#include <math.h>

#define N_PTS 16384
#define KNN   16
#define NCLS  20
#define BND_W 1.0f

#define THREADS 256
#define WAVES   4
#define FR      4                    // A fragments per wave (16 rows each)
#define RPW     (16 * FR)            // 64 rows per wave
#define RPB     (WAVES * RPW)        // 256 rows per block
#define RBLKS   (N_PTS / RPB)        // 64 row-groups
#define CSPLIT  32
#define CAND_PB (N_PTS / CSPLIT)     // 512 candidates per block (32 KB LDS)

typedef short  short8 __attribute__((ext_vector_type(8)));
typedef float  f32x4  __attribute__((ext_vector_type(4)));

// ---- bf16 helpers (RNE) ----
__device__ __forceinline__ unsigned short f2bf(float x) {
    union { __hip_bfloat16 h; unsigned short u; } cv;
    cv.h = __float2bfloat16(x);
    return cv.u;
}
__device__ __forceinline__ float bf2f(unsigned short b) {
    union { __hip_bfloat16 h; unsigned short u; } cv;
    cv.u = b;
    return __bfloat162float(cv.h);
}

// async global->LDS, 16 B per lane: LDS dest = uniform base + lane*16,
// global src = per-lane address (R5-verified pairing with pre-swizzled source)
__device__ __forceinline__ void gload16(const void* g, void* l) {
    __builtin_amdgcn_global_load_lds(
        (const __attribute__((address_space(1))) unsigned int*)g,
        (__attribute__((address_space(3))) unsigned int*)l, 16, 0, 0);
}

// Encoding tables, 32 bf16 slots per point (64 B records), built once:
//  A (center, pass1-biased): (xh,xl,xh)(yh,yl,yh)(zh,zl,zh); 9,10 = 1.0;
//    11+lab = -1024; 31 = -1024. Pass2 masks slots 11..31 to 0 in registers.
//  B (candidate, stored pre-XOR-swizzled by (i>>1)&3 in 16 B groups):
//    (xh,xh,xl)(yh,yh,yl)(zh,zh,zl); 9,10 = -h_hi,-h_lo (h=0.5|v|^2);
//    11+lab = 1.0; 31 = 1.0 iff lab==-1.
__global__ __launch_bounds__(256) void k_enc(const float* __restrict__ coord,
                                             const int* __restrict__ seg,
                                             unsigned short* __restrict__ aenc,
                                             unsigned short* __restrict__ benc,
                                             int* __restrict__ cnt,
                                             float* __restrict__ accum,
                                             int* __restrict__ done_rb,
                                             unsigned* __restrict__ done_final) {
    const int i = blockIdx.x * 256 + threadIdx.x;
    float x = coord[3 * i], y = coord[3 * i + 1], z = coord[3 * i + 2];
    int lab = seg[i];
    unsigned short xh = f2bf(x), yh = f2bf(y), zh = f2bf(z);
    unsigned short xl = f2bf(x - bf2f(xh));
    unsigned short yl = f2bf(y - bf2f(yh));
    unsigned short zl = f2bf(z - bf2f(zh));
    float h = 0.5f * fmaf(x, x, fmaf(y, y, z * z));
    unsigned short hh = f2bf(h);
    unsigned short hl = f2bf(h - bf2f(hh));
    const unsigned short one = 0x3F80u, nb = 0xC480u;  // 1.0, -1024.0

    __attribute__((aligned(16))) unsigned short a[32], b[32];
    a[0] = xh; a[1] = xl; a[2] = xh;
    a[3] = yh; a[4] = yl; a[5] = yh;
    a[6] = zh; a[7] = zl; a[8] = zh;
    a[9] = one; a[10] = one;
#pragma unroll
    for (int s = 0; s < NCLS; s++) a[11 + s] = (lab == s) ? nb : 0u;
    a[31] = nb;

    b[0] = xh; b[1] = xh; b[2] = xl;
    b[3] = yh; b[4] = yh; b[5] = yl;
    b[6] = zh; b[7] = zh; b[8] = zl;
    b[9]  = hh ^ 0x8000u;
    b[10] = hl ^ 0x8000u;
#pragma unroll
    for (int s = 0; s < NCLS; s++) b[11 + s] = (lab == s) ? one : 0u;
    b[31] = (lab < 0) ? one : 0u;

    short8* ap = (short8*)(aenc + (size_t)i * 32);
    short8* bp = (short8*)(benc + (size_t)i * 32);
    const int swz = (i >> 1) & 3;
#pragma unroll
    for (int kb = 0; kb < 4; kb++) {
        ap[kb] = ((const short8*)a)[kb];
        bp[kb ^ swz] = ((const short8*)b)[kb];
    }

    cnt[i] = 0;
    if (i < 4) accum[i] = 0.f;
    if (i == 4) *done_final = 0u;
    if (i >= 8 && i < 8 + RBLKS) done_rb[i - 8] = 0;
}

__device__ __forceinline__ float waveReduceSum(float v) {
#pragma unroll
    for (int off = 32; off > 0; off >>= 1) v += __shfl_down(v, off, 64);
    return v;
}

// PASS1: per-(row,split) max of biased scores -> smax_part[row][split] (transposed).
// PASS2: count s > thr per row (atomicAdd cnt); last split-block per row-group
//        runs the CE tail for its 256 rows; last row-group writes the loss.
template<bool PASS1>
__global__ __launch_bounds__(THREADS, 6) void k_pass(
    const unsigned short* __restrict__ aenc,
    const unsigned short* __restrict__ benc,
    const int* __restrict__ seg, const float* __restrict__ logits,
    float* __restrict__ smax_part, int* __restrict__ cnt,
    float* __restrict__ accum, int* __restrict__ done_rb,
    unsigned* __restrict__ done_final, float* __restrict__ out)
{
    __shared__ __align__(16) unsigned short bsm[CAND_PB * 32];  // 32 KB
    __shared__ float thr_lds[RPB];
    __shared__ int s_flag;
    const int tid  = threadIdx.x;
    const int lane = tid & 63, wave = tid >> 6;
    const int l15  = lane & 15, l4 = lane >> 4;
    const int rb   = blockIdx.x * RPB;
    const int split = blockIdx.y;
    const int cb   = split * CAND_PB;

    // ---- stage B slice: pure DMA (8 x 1 KB per wave), zero VALU ----
    {
        const char* gsrc = (const char*)benc + (size_t)cb * 64;
#pragma unroll
        for (int r = 0; r < 8; r++)
            gload16(gsrc + (wave * 8 + r) * 1024 + lane * 16,
                    (char*)bsm + (wave * 8 + r) * 1024);
    }

    // ---- A fragments straight from global (L2-hot) ----
    short8 af[FR];
#pragma unroll
    for (int f = 0; f < FR; f++)
        af[f] = *(const short8*)(aenc + (size_t)(rb + wave * RPW + f * 16 + l15) * 32 + l4 * 8);
    if (!PASS1) {
        // zero label/bias slots (exact: masked products contribute +-0.0)
#pragma unroll
        for (int f = 0; f < FR; f++) {
            union { short8 s; unsigned u[4]; } cv_;
            cv_.s = af[f];
            if (l4 == 1) { cv_.u[1] &= 0x0000FFFFu; cv_.u[2] = 0u; cv_.u[3] = 0u; }
            else if (l4 >= 2) { cv_.u[0] = 0u; cv_.u[1] = 0u; cv_.u[2] = 0u; cv_.u[3] = 0u; }
            af[f] = cv_.s;
        }
    }

    // ---- pass2: per-row threshold = max over 32 contiguous split partials ----
    if (!PASS1) {
        const f32x4* sp = (const f32x4*)(smax_part + (size_t)(rb + tid) * CSPLIT);
        float m = -3.0e38f;
#pragma unroll
        for (int q = 0; q < CSPLIT / 4; q++) {
            f32x4 v = sp[q];
            m = fmaxf(fmaxf(fmaxf(m, v[0]), fmaxf(v[1], v[2])), v[3]);
        }
        thr_lds[tid] = m;
    }
    __syncthreads();   // DMA drained (vmcnt) + thr_lds visible

    float thr[FR][4];
    if (!PASS1) {
#pragma unroll
        for (int f = 0; f < FR; f++)
#pragma unroll
            for (int r = 0; r < 4; r++)
                thr[f][r] = thr_lds[wave * RPW + f * 16 + l4 * 4 + r];
    }

    f32x4 rmax[FR];
    int cv[FR][4];
#pragma unroll
    for (int f = 0; f < FR; f++)
#pragma unroll
        for (int r = 0; r < 4; r++) { rmax[f][r] = -3.0e38f; cv[f][r] = 0; }

    const short8* bp = (const short8*)bsm;
    const int bidx = l15 * 4 + (l4 ^ ((l15 >> 1) & 3));
    const f32x4 zero = {0.f, 0.f, 0.f, 0.f};

    // ---- sweep: per 32 cands: 2 ds_read_b128 + 8 MFMA ----
#pragma unroll 2
    for (int c0 = 0; c0 < CAND_PB; c0 += 32) {
        short8 bA = bp[bidx + c0 * 4];
        short8 bB = bp[bidx + (c0 + 16) * 4];
        f32x4 dA[FR], dB[FR];
#pragma unroll
        for (int f = 0; f < FR; f++)
            dA[f] = __builtin_amdgcn_mfma_f32_16x16x32_bf16(af[f], bA, zero, 0, 0, 0);
#pragma unroll
        for (int f = 0; f < FR; f++)
            dB[f] = __builtin_amdgcn_mfma_f32_16x16x32_bf16(af[f], bB, zero, 0, 0, 0);
        if (PASS1) {
#pragma unroll
            for (int f = 0; f < FR; f++)
#pragma unroll
                for (int r = 0; r < 4; r++)
                    rmax[f][r] = fmaxf(fmaxf(rmax[f][r], dA[f][r]), dB[f][r]);
        } else {
#pragma unroll
            for (int f = 0; f < FR; f++)
#pragma unroll
                for (int r = 0; r < 4; r++)
                    cv[f][r] += ((dA[f][r] > thr[f][r]) ? 1 : 0)
                              + ((dB[f][r] > thr[f][r]) ? 1 : 0);
        }
    }

    // ---- reduce across the 16 column-lanes; write ----
    if (PASS1) {
#pragma unroll
        for (int m = 1; m < 16; m <<= 1)
#pragma unroll
            for (int f = 0; f < FR; f++)
#pragma unroll
                for (int r = 0; r < 4; r++)
                    rmax[f][r] = fmaxf(rmax[f][r], __shfl_xor(rmax[f][r], m, 64));
        if (l15 == 0) {
#pragma unroll
            for (int f = 0; f < FR; f++)
#pragma unroll
                for (int r = 0; r < 4; r++)
                    smax_part[(size_t)(rb + wave * RPW + f * 16 + l4 * 4 + r) * CSPLIT + split]
                        = rmax[f][r];
        }
    } else {
#pragma unroll
        for (int m = 1; m < 16; m <<= 1)
#pragma unroll
            for (int f = 0; f < FR; f++)
#pragma unroll
                for (int r = 0; r < 4; r++)
                    cv[f][r] += __shfl_xor(cv[f][r], m, 64);
        if (l15 == 0) {
#pragma unroll
            for (int f = 0; f < FR; f++)
#pragma unroll
                for (int r = 0; r < 4; r++)
                    atomicAdd(&cnt[rb + wave * RPW + f * 16 + l4 * 4 + r], cv[f][r]);
        }

        // ---- CE tail: last split-block of this row-group handles its 256 rows ----
        __syncthreads();
        if (tid == 0) {
            __threadfence();
            s_flag = (atomicAdd(&done_rb[blockIdx.x], 1) == CSPLIT - 1) ? 1 : 0;
        }
        __syncthreads();
        if (s_flag) {
            const int row = rb + tid;
            int sg = seg[row];
            bool valid = (sg != -1);
            const float4* row4 = (const float4*)(logits + (size_t)row * NCLS);
            float a[NCLS];
            float4 v0 = row4[0], v1 = row4[1], v2 = row4[2], v3 = row4[3], v4 = row4[4];
            a[0]=v0.x; a[1]=v0.y; a[2]=v0.z; a[3]=v0.w;
            a[4]=v1.x; a[5]=v1.y; a[6]=v1.z; a[7]=v1.w;
            a[8]=v2.x; a[9]=v2.y; a[10]=v2.z; a[11]=v2.w;
            a[12]=v3.x; a[13]=v3.y; a[14]=v3.z; a[15]=v3.w;
            a[16]=v4.x; a[17]=v4.y; a[18]=v4.z; a[19]=v4.w;
            float mx = a[0];
#pragma unroll
            for (int c = 1; c < NCLS; c++) mx = fmaxf(mx, a[c]);
            float se = 0.f;
#pragma unroll
            for (int c = 0; c < NCLS; c++) se += __expf(a[c] - mx);
            int tgt = min(max(sg, 0), NCLS - 1);
            float at = 0.f;
#pragma unroll
            for (int c = 0; c < NCLS; c++) at += (c == tgt) ? a[c] : 0.f;
            float logp = at - mx - __logf(se);
            int crow = atomicAdd(&cnt[row], 0);   // coherent read
            // cnt includes self once; boundary iff rank of nearest-diff < K
            bool bnd = valid && ((crow - 1) < KNN);
            float sm = valid ? logp : 0.f, nm = valid ? 1.f : 0.f;
            float sb = bnd ? logp : 0.f,  nb2 = bnd ? 1.f : 0.f;
            sm = waveReduceSum(sm); nm = waveReduceSum(nm);
            sb = waveReduceSum(sb); nb2 = waveReduceSum(nb2);
            if ((tid & 63) == 0) {
                atomicAdd(&accum[0], sm);
                atomicAdd(&accum[1], nm);
                atomicAdd(&accum[2], sb);
                atomicAdd(&accum[3], nb2);
            }
            __syncthreads();
            if (tid == 0) {
                __threadfence();
                if (atomicAdd(done_final, 1u) == (unsigned)(RBLKS - 1)) {
                    float Sm = atomicAdd(&accum[0], 0.f);
                    float Cm = atomicAdd(&accum[1], 0.f);
                    float Sb = atomicAdd(&accum[2], 0.f);
                    float Cb = atomicAdd(&accum[3], 0.f);
                    float main_loss = (Cm > 0.f) ? (-Sm / fmaxf(Cm, 1.f)) : 0.f;
                    float bnd_loss  = (Cb > 0.f) ? (-Sb / fmaxf(Cb, 1.f)) : 0.f;
                    out[0] = main_loss + BND_W * bnd_loss;
                }
            }
        }
    }
}

extern "C" void kernel_launch(void* const* d_in, const int* in_sizes, int n_in,
                              void* d_out, int out_size, void* d_ws, size_t ws_size,
                              hipStream_t stream) {
    const float* coord  = (const float*)d_in[0];
    const float* logits = (const float*)d_in[1];
    const int*   seg    = (const int*)d_in[2];
    (void)in_sizes; (void)n_in; (void)out_size; (void)ws_size;

    unsigned short* aenc = (unsigned short*)d_ws;                         // 1 MB
    unsigned short* benc = (unsigned short*)((char*)d_ws + (1u << 20));   // 1 MB
    float* smax_part = (float*)((char*)d_ws + (2u << 20));                // [N][32] f32, 2 MB
    int*   cnt       = (int*)((char*)d_ws + (4u << 20));                  // [N] i32
    char*  tail      = (char*)d_ws + (4u << 20) + N_PTS * 4;
    float*    accum      = (float*)tail;                                  // 4 f32
    unsigned* done_final = (unsigned*)(tail + 16);
    int*      done_rb    = (int*)(tail + 32);                             // 64 i32

    dim3 grid(RBLKS, CSPLIT);
    k_enc        <<<N_PTS / 256, 256, 0, stream>>>(coord, seg, aenc, benc, cnt,
                                                   accum, done_rb, done_final);
    k_pass<true> <<<grid, THREADS, 0, stream>>>(aenc, benc, seg, logits, smax_part, cnt,
                                                accum, done_rb, done_final, (float*)d_out);
    k_pass<false><<<grid, THREADS, 0, stream>>>(aenc, benc, seg, logits, smax_part, cnt,
                                                accum, done_rb, done_final, (float*)d_out);
}

// Round 12
// 84.201 us; speedup vs baseline: 1.0918x; 1.0918x over previous
//
#include <hip/hip_runtime.h>
#include <hip/hip_bf16.h>
#include <math.h>

#define N_PTS 16384
#define KNN   16
#define NCLS  20
#define BND_W 1.0f

#define THREADS 512
#define WAVES   8
#define RPB     64                   // rows per block (4 frags of 16; shared by all waves)
#define NBLK    (N_PTS / RPB)        // 256 blocks = 1 per CU
#define CHUNK   1024                 // candidates per LDS chunk (64 KB)
#define NCHUNK  (N_PTS / CHUNK)      // 16
#define TILES   (CHUNK / 16)         // 64 col-tiles per chunk
#define TPW     (TILES / WAVES)      // 8 tiles per wave per chunk

typedef short  short8 __attribute__((ext_vector_type(8)));
typedef float  f32x4  __attribute__((ext_vector_type(4)));

// ---- bf16 helpers (RNE) ----
__device__ __forceinline__ unsigned short f2bf(float x) {
    union { __hip_bfloat16 h; unsigned short u; } cv;
    cv.h = __float2bfloat16(x);
    return cv.u;
}
__device__ __forceinline__ float bf2f(unsigned short b) {
    union { __hip_bfloat16 h; unsigned short u; } cv;
    cv.u = b;
    return __bfloat162float(cv.h);
}

// async global->LDS, 16 B/lane: LDS dest = wave-uniform base (+lane*16 by HW),
// global src per-lane (R5/R10-verified pairing with pre-swizzled source)
__device__ __forceinline__ void gload16(const void* g, void* l) {
    __builtin_amdgcn_global_load_lds(
        (const __attribute__((address_space(1))) unsigned int*)g,
        (__attribute__((address_space(3))) unsigned int*)l, 16, 0, 0);
}

// B record (64 B, 32 bf16 slots), stored pre-XOR-swizzled by (i>>1)&3 in 16 B
// groups:  0..8 (xh,xh,xl)(yh,yh,yl)(zh,zh,zl); 9,10 = -h_hi,-h_lo (h=0.5|v|^2);
// 11+lab = 1.0; 31 = 1.0 iff lab==-1.
__global__ __launch_bounds__(256) void k_enc(const float* __restrict__ coord,
                                             const int* __restrict__ seg,
                                             unsigned short* __restrict__ benc,
                                             float* __restrict__ accum,
                                             unsigned* __restrict__ done_final) {
    const int i = blockIdx.x * 256 + threadIdx.x;
    float x = coord[3 * i], y = coord[3 * i + 1], z = coord[3 * i + 2];
    int lab = seg[i];
    unsigned short xh = f2bf(x), yh = f2bf(y), zh = f2bf(z);
    unsigned short xl = f2bf(x - bf2f(xh));
    unsigned short yl = f2bf(y - bf2f(yh));
    unsigned short zl = f2bf(z - bf2f(zh));
    float h = 0.5f * fmaf(x, x, fmaf(y, y, z * z));
    unsigned short hh = f2bf(h);
    unsigned short hl = f2bf(h - bf2f(hh));
    const unsigned short one = 0x3F80u;

    __attribute__((aligned(16))) unsigned short b[32];
    b[0] = xh; b[1] = xh; b[2] = xl;
    b[3] = yh; b[4] = yh; b[5] = yl;
    b[6] = zh; b[7] = zh; b[8] = zl;
    b[9]  = hh ^ 0x8000u;
    b[10] = hl ^ 0x8000u;
#pragma unroll
    for (int s = 0; s < NCLS; s++) b[11 + s] = (lab == s) ? one : 0u;
    b[31] = (lab < 0) ? one : 0u;

    short8* bp = (short8*)(benc + (size_t)i * 32);
    const int swz = (i >> 1) & 3;
#pragma unroll
    for (int kb = 0; kb < 4; kb++) bp[kb ^ swz] = ((const short8*)b)[kb];

    if (i < 4) accum[i] = 0.f;
    if (i == 4) *done_final = 0u;
}

// Center (A) fragment, pass1-biased:
//  0..8 (xh,xl,xh)(yh,yl,yh)(zh,zl,zh); 9,10 = 1.0; 11+lab = -1024; 31 = -1024.
// Lane supplies row's slots g*8..g*8+7 (g = lane>>4).
__device__ __forceinline__ short8 build_a_frag(const float* __restrict__ coord,
                                               const int* __restrict__ seg,
                                               int row, int g) {
    __attribute__((aligned(16))) unsigned short s[8];
    const unsigned short one = 0x3F80u, nb = 0xC480u;   // 1.0, -1024.0
    if (g == 0) {
        float x = coord[3 * row], y = coord[3 * row + 1], z = coord[3 * row + 2];
        unsigned short xh = f2bf(x), yh = f2bf(y), zh = f2bf(z);
        s[0] = xh; s[1] = f2bf(x - bf2f(xh)); s[2] = xh;
        s[3] = yh; s[4] = f2bf(y - bf2f(yh)); s[5] = yh;
        s[6] = zh; s[7] = f2bf(z - bf2f(zh));
    } else if (g == 1) {
        float z = coord[3 * row + 2];
        int lab = seg[row];
        s[0] = f2bf(z); s[1] = one; s[2] = one;
        s[3] = (lab == 0) ? nb : 0u; s[4] = (lab == 1) ? nb : 0u;
        s[5] = (lab == 2) ? nb : 0u; s[6] = (lab == 3) ? nb : 0u;
        s[7] = (lab == 4) ? nb : 0u;
    } else if (g == 2) {
        int lab = seg[row];
        s[0] = (lab == 5) ? nb : 0u;  s[1] = (lab == 6) ? nb : 0u;
        s[2] = (lab == 7) ? nb : 0u;  s[3] = (lab == 8) ? nb : 0u;
        s[4] = (lab == 9) ? nb : 0u;  s[5] = (lab == 10) ? nb : 0u;
        s[6] = (lab == 11) ? nb : 0u; s[7] = (lab == 12) ? nb : 0u;
    } else {
        int lab = seg[row];
        s[0] = (lab == 13) ? nb : 0u; s[1] = (lab == 14) ? nb : 0u;
        s[2] = (lab == 15) ? nb : 0u; s[3] = (lab == 16) ? nb : 0u;
        s[4] = (lab == 17) ? nb : 0u; s[5] = (lab == 18) ? nb : 0u;
        s[6] = (lab == 19) ? nb : 0u; s[7] = nb;   // slot 31 (invalid-cand mask)
    }
    return *(const short8*)s;
}

__device__ __forceinline__ float waveReduceSum(float v) {
#pragma unroll
    for (int off = 32; off > 0; off >>= 1) v += __shfl_down(v, off, 64);
    return v;
}

// Self-contained block: 64 rows, sweeps all candidates twice (max, then count),
// block-local threshold, fused CE. No inter-block dependencies except the final
// scalar accumulation.
__global__ __launch_bounds__(THREADS, 2) void k_main(
    const float* __restrict__ coord, const int* __restrict__ seg,
    const float* __restrict__ logits, const unsigned short* __restrict__ benc,
    float* __restrict__ accum, unsigned* __restrict__ done_final,
    float* __restrict__ out)
{
    __shared__ __align__(16) unsigned short bsm[2][CHUNK * 32];  // 2 x 64 KB
    __shared__ float wsm[WAVES * RPB];                           // wave partials (2 KB)
    __shared__ float thr_lds[RPB];
    const int tid  = threadIdx.x;
    const int lane = tid & 63, wave = tid >> 6;
    const int l15  = lane & 15, l4 = lane >> 4;
    const int rb   = blockIdx.x * RPB;

    // ---- A fragments (pass1-biased); rows shared by all waves ----
    short8 af[4];
#pragma unroll
    for (int f = 0; f < 4; f++)
        af[f] = build_a_frag(coord, seg, rb + f * 16 + l15, l4);

    const int bidx = l15 * 4 + (l4 ^ ((l15 >> 1) & 3));
    const f32x4 zero = {0.f, 0.f, 0.f, 0.f};

    // ---- stage chunk 0 ----
    {
        const char* g = (const char*)benc;
#pragma unroll
        for (int r = 0; r < 8; r++)
            gload16(g + (wave * 8 + r) * 1024 + lane * 16,
                    (char*)bsm[0] + (wave * 8 + r) * 1024);
    }

    // ================= PASS 1: row-max over diff-labeled =================
    f32x4 rmax[4];
#pragma unroll
    for (int f = 0; f < 4; f++)
#pragma unroll
        for (int r = 0; r < 4; r++) rmax[f][r] = -3.0e38f;

    for (int ch = 0; ch < NCHUNK; ch++) {
        const int b = ch & 1;
        __syncthreads();   // chunk b DMA complete; buffer b^1 free
        if (ch + 1 < NCHUNK) {
            const char* g = (const char*)benc + (size_t)(ch + 1) * CHUNK * 64;
#pragma unroll
            for (int r = 0; r < 8; r++)
                gload16(g + (wave * 8 + r) * 1024 + lane * 16,
                        (char*)bsm[b ^ 1] + (wave * 8 + r) * 1024);
        }
        const short8* bp = (const short8*)bsm[b];
#pragma unroll
        for (int t = 0; t < TPW; t++) {
            short8 bf = bp[(wave + t * WAVES) * 64 + bidx];
            f32x4 d[4];
#pragma unroll
            for (int f = 0; f < 4; f++)
                d[f] = __builtin_amdgcn_mfma_f32_16x16x32_bf16(af[f], bf, zero, 0, 0, 0);
#pragma unroll
            for (int f = 0; f < 4; f++)
#pragma unroll
                for (int r = 0; r < 4; r++)
                    rmax[f][r] = fmaxf(rmax[f][r], d[f][r]);
        }
    }

    // ---- block-local threshold: reduce 16 col-lanes, then 8 waves ----
#pragma unroll
    for (int m = 1; m < 16; m <<= 1)
#pragma unroll
        for (int f = 0; f < 4; f++)
#pragma unroll
            for (int r = 0; r < 4; r++)
                rmax[f][r] = fmaxf(rmax[f][r], __shfl_xor(rmax[f][r], m, 64));
    __syncthreads();   // all waves done with bsm[last] before reuse of wsm region
    if (l15 == 0) {
#pragma unroll
        for (int f = 0; f < 4; f++)
#pragma unroll
            for (int r = 0; r < 4; r++)
                wsm[wave * RPB + f * 16 + l4 * 4 + r] = rmax[f][r];
    }
    __syncthreads();
    if (tid < RPB) {
        float m = wsm[tid];
#pragma unroll
        for (int w = 1; w < WAVES; w++) m = fmaxf(m, wsm[w * RPB + tid]);
        thr_lds[tid] = m;
    }
    // re-mask A for pass 2: zero label/bias slots (exact +-0 products)
#pragma unroll
    for (int f = 0; f < 4; f++) {
        union { short8 s; unsigned u[4]; } cv_;
        cv_.s = af[f];
        if (l4 == 1) { cv_.u[1] &= 0x0000FFFFu; cv_.u[2] = 0u; cv_.u[3] = 0u; }
        else if (l4 >= 2) { cv_.u[0] = 0u; cv_.u[1] = 0u; cv_.u[2] = 0u; cv_.u[3] = 0u; }
        af[f] = cv_.s;
    }
    // stage chunk 0 for pass 2
    {
        const char* g = (const char*)benc;
#pragma unroll
        for (int r = 0; r < 8; r++)
            gload16(g + (wave * 8 + r) * 1024 + lane * 16,
                    (char*)bsm[0] + (wave * 8 + r) * 1024);
    }
    __syncthreads();   // thr_lds visible (DMA drained at next loop-top barrier too)

    float thr[4][4];
    int cv[4][4];
#pragma unroll
    for (int f = 0; f < 4; f++)
#pragma unroll
        for (int r = 0; r < 4; r++) {
            thr[f][r] = thr_lds[f * 16 + l4 * 4 + r];
            cv[f][r] = 0;
        }

    // ================= PASS 2: count s > thr (bit-identical scores) =================
    for (int ch = 0; ch < NCHUNK; ch++) {
        const int b = ch & 1;
        __syncthreads();
        if (ch + 1 < NCHUNK) {
            const char* g = (const char*)benc + (size_t)(ch + 1) * CHUNK * 64;
#pragma unroll
            for (int r = 0; r < 8; r++)
                gload16(g + (wave * 8 + r) * 1024 + lane * 16,
                        (char*)bsm[b ^ 1] + (wave * 8 + r) * 1024);
        }
        const short8* bp = (const short8*)bsm[b];
#pragma unroll
        for (int t = 0; t < TPW; t++) {
            short8 bf = bp[(wave + t * WAVES) * 64 + bidx];
            f32x4 d[4];
#pragma unroll
            for (int f = 0; f < 4; f++)
                d[f] = __builtin_amdgcn_mfma_f32_16x16x32_bf16(af[f], bf, zero, 0, 0, 0);
#pragma unroll
            for (int f = 0; f < 4; f++)
#pragma unroll
                for (int r = 0; r < 4; r++)
                    cv[f][r] += (d[f][r] > thr[f][r]) ? 1 : 0;
        }
    }

    // ---- merge counts: 16 col-lanes, then 8 waves ----
#pragma unroll
    for (int m = 1; m < 16; m <<= 1)
#pragma unroll
        for (int f = 0; f < 4; f++)
#pragma unroll
            for (int r = 0; r < 4; r++)
                cv[f][r] += __shfl_xor(cv[f][r], m, 64);
    __syncthreads();
    int* ism = (int*)wsm;
    if (l15 == 0) {
#pragma unroll
        for (int f = 0; f < 4; f++)
#pragma unroll
            for (int r = 0; r < 4; r++)
                ism[wave * RPB + f * 16 + l4 * 4 + r] = cv[f][r];
    }
    __syncthreads();

    // ---- CE tail for this block's 64 rows (wave 0) ----
    if (tid < RPB) {
        const int row = rb + tid;
        int crow = ism[tid];
#pragma unroll
        for (int w = 1; w < WAVES; w++) crow += ism[w * RPB + tid];
        int sg = seg[row];
        bool valid = (sg != -1);
        const float4* row4 = (const float4*)(logits + (size_t)row * NCLS);
        float a[NCLS];
        float4 v0 = row4[0], v1 = row4[1], v2 = row4[2], v3 = row4[3], v4 = row4[4];
        a[0]=v0.x; a[1]=v0.y; a[2]=v0.z; a[3]=v0.w;
        a[4]=v1.x; a[5]=v1.y; a[6]=v1.z; a[7]=v1.w;
        a[8]=v2.x; a[9]=v2.y; a[10]=v2.z; a[11]=v2.w;
        a[12]=v3.x; a[13]=v3.y; a[14]=v3.z; a[15]=v3.w;
        a[16]=v4.x; a[17]=v4.y; a[18]=v4.z; a[19]=v4.w;
        float mx = a[0];
#pragma unroll
        for (int c = 1; c < NCLS; c++) mx = fmaxf(mx, a[c]);
        float se = 0.f;
#pragma unroll
        for (int c = 0; c < NCLS; c++) se += __expf(a[c] - mx);
        int tgt = min(max(sg, 0), NCLS - 1);
        float at = 0.f;
#pragma unroll
        for (int c = 0; c < NCLS; c++) at += (c == tgt) ? a[c] : 0.f;
        float logp = at - mx - __logf(se);
        // crow includes self exactly once; boundary iff rank of nearest-diff < K
        bool bnd = valid && ((crow - 1) < KNN);
        float sm = valid ? logp : 0.f, nm = valid ? 1.f : 0.f;
        float sb = bnd ? logp : 0.f,  nb2 = bnd ? 1.f : 0.f;
        sm = waveReduceSum(sm); nm = waveReduceSum(nm);
        sb = waveReduceSum(sb); nb2 = waveReduceSum(nb2);
        if (tid == 0) {
            atomicAdd(&accum[0], sm);
            atomicAdd(&accum[1], nm);
            atomicAdd(&accum[2], sb);
            atomicAdd(&accum[3], nb2);
        }
    }
    __syncthreads();
    if (tid == 0) {
        __threadfence();
        if (atomicAdd(done_final, 1u) == (unsigned)(NBLK - 1)) {
            float Sm = atomicAdd(&accum[0], 0.f);
            float Cm = atomicAdd(&accum[1], 0.f);
            float Sb = atomicAdd(&accum[2], 0.f);
            float Cb = atomicAdd(&accum[3], 0.f);
            float main_loss = (Cm > 0.f) ? (-Sm / fmaxf(Cm, 1.f)) : 0.f;
            float bnd_loss  = (Cb > 0.f) ? (-Sb / fmaxf(Cb, 1.f)) : 0.f;
            out[0] = main_loss + BND_W * bnd_loss;
        }
    }
}

extern "C" void kernel_launch(void* const* d_in, const int* in_sizes, int n_in,
                              void* d_out, int out_size, void* d_ws, size_t ws_size,
                              hipStream_t stream) {
    const float* coord  = (const float*)d_in[0];
    const float* logits = (const float*)d_in[1];
    const int*   seg    = (const int*)d_in[2];
    (void)in_sizes; (void)n_in; (void)out_size; (void)ws_size;

    unsigned short* benc = (unsigned short*)d_ws;                    // 1 MB
    float*    accum      = (float*)((char*)d_ws + (1u << 20));       // 4 f32
    unsigned* done_final = (unsigned*)((char*)d_ws + (1u << 20) + 16);

    k_enc <<<N_PTS / 256, 256, 0, stream>>>(coord, seg, benc, accum, done_final);
    k_main<<<NBLK, THREADS, 0, stream>>>(coord, seg, logits, benc,
                                         accum, done_final, (float*)d_out);
}